// Round 7
// baseline (218.920 us; speedup 1.0000x reference)
//
#include <hip/hip_runtime.h>
#include <hip/hip_bf16.h>

#define B_DIM 8
#define C_DIM 256
#define S_DIM 2304

// srcT/dstT layout: MFMA-fragment-tiled  [B][S/16][C/8][16 rows][8 k]
//   T(s,c) = (s>>4)*4096 + (c>>3)*128 + (s&15)*8 + (c&7)      (elems)

typedef __attribute__((ext_vector_type(8))) short short8;
typedef __attribute__((ext_vector_type(4))) float floatx4;

__device__ __forceinline__ void barrier_lgkm() {
    asm volatile("s_waitcnt lgkmcnt(0)\n\ts_barrier" ::: "memory");
}

// ---------------------------------------------------------------------------
// Kernel 1: per-(b,s) L2-normalize over C, f32 [B,C,S] -> bf16 tiled layout.
// Exact R6 verified version (b128 XOR-swizzled LDS staging, conflict-free).
// ---------------------------------------------------------------------------
__global__ __launch_bounds__(256) void norm_transpose_kernel(
    const float* __restrict__ src, const float* __restrict__ dst,
    __hip_bfloat16* __restrict__ srcT, __hip_bfloat16* __restrict__ dstT) {
    const int s0 = blockIdx.x * 64;
    const int b  = blockIdx.y;
    const float* in = (blockIdx.z == 0 ? src : dst) + (size_t)b * C_DIM * S_DIM;
    __hip_bfloat16* out = (blockIdx.z == 0 ? srcT : dstT) + (size_t)b * S_DIM * C_DIM;

    __shared__ __align__(16) __hip_bfloat16 tile[64][C_DIM];   // 32 KB, swizzled
    __shared__ float red[4][64];
    __shared__ float invn[64];

    const int t  = threadIdx.x;
    const int l  = t & 63;
    const int wv = t >> 6;

    float ss = 0.f;
#pragma unroll 2
    for (int q = 0; q < 8; ++q) {
        int oct = 4 * q + wv;
        union { short8 v; __hip_bfloat16 h[8]; } o;
#pragma unroll
        for (int j = 0; j < 8; ++j) {
            float v = in[(size_t)(oct * 8 + j) * S_DIM + s0 + l];
            ss += v * v;
            o.h[j] = __float2bfloat16(v);
        }
        *(short8*)((char*)&tile[l][0] + ((oct * 16) ^ ((l & 7) << 4))) = o.v;
    }
    red[wv][l] = ss;
    __syncthreads();
    if (t < 64) invn[t] = rsqrtf(red[0][t] + red[1][t] + red[2][t] + red[3][t]);
    __syncthreads();

#pragma unroll
    for (int it = 0; it < 8; ++it) {
        int gidx = it * 256 + t;
        int fm   = gidx & 15;
        int cg   = (gidx >> 4) & 31;
        int sg   = gidx >> 9;
        int srow = sg * 16 + fm;
        float inv = invn[srow];
        union { short8 v; __hip_bfloat16 h[8]; } u, o;
        u.v = *(const short8*)((const char*)&tile[srow][0]
                               + ((cg * 16) ^ ((srow & 7) << 4)));
#pragma unroll
        for (int j = 0; j < 8; ++j)
            o.h[j] = __float2bfloat16(__bfloat162float(u.h[j]) * inv);
        *(short8*)&out[(size_t)((s0 >> 4) + sg) * 4096 + cg * 128 + fm * 8] = o.v;
    }
}

// ---------------------------------------------------------------------------
// Kernel 2: per-batch GEMM, 256x256 tile (was 128x128).
// WHY: the binding cost is A/B panel traffic out of Infinity Cache. 128^2
// direct-frag blocks read 256 KB each (A,B read 2x by wave pairs) -> 664 MB
// aggregate. 256^2 + LDS staging reads each panel byte ONCE: 648 blocks x
// 256 KB = 166 MB (4x less). Pipeline = R0's proven cp.async-style loop:
//   iter ki: ds_write regs->buf[ki&1]; prefetch ki+1 regs (in flight across
//   barrier); s_waitcnt lgkmcnt(0); s_barrier; frag ds_reads; 32x MFMA.
// 512 thr (8 waves, 2x4 wave grid, 128x64 per wave), K-step 32, dbuf LDS
// 64 KB; VGPR ~ acc128+frag48+stage32+addr < 256 @ __launch_bounds__(512,2).
// LDS tile layout = image of global tiled segments: seg s=(g,c) at elems
// s*128 + (t&15)*8; frag read addr (g*4 + lane>>4)*128 + fm*8 -> b128 reads,
// uniform 8 lanes per bank-quad per phase = conflict-free.
// Epilogue: 4 slabs of 64 rows through Cs[64][260] (proven pattern), dense
// NT floatx4 stores.
// ---------------------------------------------------------------------------
__global__ __launch_bounds__(512, 2) void gemm_relu_kernel(
    const __hip_bfloat16* __restrict__ At, const __hip_bfloat16* __restrict__ Bt,
    float* __restrict__ out) {
    const int id = blockIdx.x;
    const int b  = id & 7;          // batch -> XCD round-robin (648 % 8 == 0)
    const int q  = id >> 3;         // 0..80
    const int m0 = (q % 9) * 256;
    const int n0 = (q / 9) * 256;

    // LDS: buf k at elems [k*16384): A 8192 | B 8192   (64 KB total)
    // epilogue Cs[64][260] f32 = 66560 B aliased on top.
    __shared__ __align__(16) unsigned char smem[66560];
    __hip_bfloat16* stg = (__hip_bfloat16*)smem;
    float* Cs = (float*)smem;

    const int t    = threadIdx.x;
    const int lane = t & 63;
    const int wv   = t >> 6;        // 0..7

    const int fm  = lane & 15;
    const int kq4 = lane >> 4;      // k-quarter 0..3
    const int rq  = kq4 << 2;
    const int wr2 = wv >> 2;        // 0..1 : m-half (128 rows)
    const int wc2 = wv & 3;         // 0..3 : n-quarter (64 cols)

    // Staging: thread t owns segments s0t = t>>4 and s0t+32 of each tile
    // (64 segs of 256 B per 16 KB tile). seg s: g = s>>2 (m/n 16-group),
    // c = s&3 (k-chunk within the K-step).
    const int seg0 = t >> 4;
    const int lq   = (t & 15);      // 16-B slot within segment
    const int sA0g = seg0 >> 2, sA0c = seg0 & 3;
    const int seg1 = seg0 + 32;
    const int sA1g = seg1 >> 2, sA1c = seg1 & 3;

    const __hip_bfloat16* Ab = At + (size_t)b * S_DIM * C_DIM;
    const __hip_bfloat16* Bb = Bt + (size_t)b * S_DIM * C_DIM;
    // global addr of (g, c, ki): ((m0>>4)+g)*4096 + (ki*4+c)*128 + lq*8
    const __hip_bfloat16* gA0 = Ab + (size_t)((m0 >> 4) + sA0g) * 4096 + sA0c * 128 + lq * 8;
    const __hip_bfloat16* gA1 = Ab + (size_t)((m0 >> 4) + sA1g) * 4096 + sA1c * 128 + lq * 8;
    const __hip_bfloat16* gB0 = Bb + (size_t)((n0 >> 4) + sA0g) * 4096 + sA0c * 128 + lq * 8;
    const __hip_bfloat16* gB1 = Bb + (size_t)((n0 >> 4) + sA1g) * 4096 + sA1c * 128 + lq * 8;
    // LDS elem offsets (within a tile): seg*128 + lq*8
    const int l0 = seg0 * 128 + lq * 8;
    const int l1 = seg1 * 128 + lq * 8;

    // prologue: K-step 0 -> regs
    short8 rA0 = *(const short8*)gA0;
    short8 rA1 = *(const short8*)gA1;
    short8 rB0 = *(const short8*)gB0;
    short8 rB1 = *(const short8*)gB1;

    floatx4 acc[8][4] = {};

#pragma unroll
    for (int ki = 0; ki < 8; ++ki) {
        __hip_bfloat16* As = stg + (ki & 1) * 16384;
        __hip_bfloat16* Bs = As + 8192;

        // stage K-step ki (vmcnt wait for loads issued one iter ago is
        // inserted by the compiler right here)
        *(short8*)(As + l0) = rA0;
        *(short8*)(As + l1) = rA1;
        *(short8*)(Bs + l0) = rB0;
        *(short8*)(Bs + l1) = rB1;

        // prefetch K-step ki+1 -> regs; stays in flight across the barrier
        if (ki < 7) {
            int off = (ki + 1) * 512;   // 4 chunks * 128 elems
            rA0 = *(const short8*)(gA0 + off);
            rA1 = *(const short8*)(gA1 + off);
            rB0 = *(const short8*)(gB0 + off);
            rB1 = *(const short8*)(gB1 + off);
        }

        barrier_lgkm();   // drain LDS writes only; NO vmcnt drain

        // fragment reads: A-frag i at g = wr2*8+i; B-frag j at g = wc2*4+j
        short8 af[8], bf[4];
#pragma unroll
        for (int i = 0; i < 8; ++i)
            af[i] = *(const short8*)&As[((wr2 * 8 + i) * 4 + kq4) * 128 + fm * 8];
#pragma unroll
        for (int j = 0; j < 4; ++j)
            bf[j] = *(const short8*)&Bs[((wc2 * 4 + j) * 4 + kq4) * 128 + fm * 8];

        __builtin_amdgcn_s_setprio(1);
#pragma unroll
        for (int i = 0; i < 8; ++i)
#pragma unroll
            for (int j = 0; j < 4; ++j)
                acc[i][j] = __builtin_amdgcn_mfma_f32_16x16x32_bf16(af[i], bf[j], acc[i][j], 0, 0, 0);
        __builtin_amdgcn_s_setprio(0);
    }

    // Epilogue: 4 slabs of 64 rows. Slab p: waves with wr2==p>>1 write
    // acc[4*(p&1)+i2][j] to Cs[i2*16+rq+r][wc2*64+j*16+fm]; then all 512
    // threads stream 64x256 f32 out as dense NT floatx4 (1 KB/wave-instr).
    float* Cp = out + (size_t)b * S_DIM * S_DIM;
#pragma unroll
    for (int p = 0; p < 4; ++p) {
        __syncthreads();   // frag ds_reads (p=0) / prior Cs reads done
        if (wr2 == (p >> 1)) {
#pragma unroll
            for (int i2 = 0; i2 < 2; ++i2) {
#pragma unroll
                for (int j = 0; j < 4; ++j) {
                    int col = wc2 * 64 + j * 16 + fm;
#pragma unroll
                    for (int r = 0; r < 4; ++r) {
                        Cs[(i2 * 16 + rq + r) * 260 + col] =
                            fmaxf(acc[4 * (p & 1) + i2][j][r], 0.f);
                        Cs[((i2 + 2) * 16 + rq + r) * 260 + col] =
                            fmaxf(acc[4 * (p & 1) + i2 + 2][j][r], 0.f);
                    }
                }
            }
        }
        __syncthreads();
#pragma unroll
        for (int it = 0; it < 8; ++it) {
            int idx  = it * 512 + t;
            int srow = idx >> 6;            // 0..63
            int c4   = (idx & 63) << 2;     // 0..252
            floatx4 v = *(const floatx4*)&Cs[srow * 260 + c4];
            __builtin_nontemporal_store(
                v, (floatx4*)&Cp[(size_t)(m0 + p * 64 + srow) * S_DIM + n0 + c4]);
        }
    }
}

extern "C" void kernel_launch(void* const* d_in, const int* in_sizes, int n_in,
                              void* d_out, int out_size, void* d_ws, size_t ws_size,
                              hipStream_t stream) {
    const float* src = (const float*)d_in[0];
    const float* dst = (const float*)d_in[1];
    float* out = (float*)d_out;

    __hip_bfloat16* srcT = (__hip_bfloat16*)d_ws;
    __hip_bfloat16* dstT = srcT + (size_t)B_DIM * S_DIM * C_DIM;

    dim3 g1(S_DIM / 64, B_DIM, 2);
    norm_transpose_kernel<<<g1, 256, 0, stream>>>(src, dst, srcT, dstT);

    gemm_relu_kernel<<<dim3(B_DIM * 9 * 9), 512, 0, stream>>>(srcT, dstT, out);
}

// Round 8
// 209.938 us; speedup vs baseline: 1.0428x; 1.0428x over previous
//
#include <hip/hip_runtime.h>
#include <hip/hip_bf16.h>

#define B_DIM 8
#define C_DIM 256
#define S_DIM 2304

// srcT/dstT layout: MFMA-fragment-tiled  [B][S/16][C/8][16 rows][8 k]
//   T(s,c) = (s>>4)*4096 + (c>>3)*128 + (s&15)*8 + (c&7)      (elems)
// A wave's A/B fragment load for mfma_16x16x32_bf16 becomes base + lane*16B
// -> one fully coalesced 1 KB global_load_dwordx4 from the XCD-resident L2.

typedef __attribute__((ext_vector_type(8))) short short8;
typedef __attribute__((ext_vector_type(4))) float floatx4;

// ---------------------------------------------------------------------------
// Kernel 1: per-(b,s) L2-normalize over C, f32 [B,C,S] -> bf16 tiled layout.
// THIS ROUND: 32 s-rows per block (was 64) -> 1152 blocks = 4.5/CU.
// Rationale: at 576 blocks (2.25/CU) the tail generation left 3/4 of CUs
// idle for ~1 block-time (~5-8 us of the norm's ~35). Finer quanta smooth
// the tail; LDS 16.5 KB; in-flight bytes/CU ~2x (better latency cover).
// Loads: two 128-B segments per instruction (full L2 lines, coalesced).
// LDS staging keeps the R6-verified b128 XOR-swizzle involution
// (byteInRow = 16*oct ^ 16*(row&7)): per-instruction slot density is even
// -> LDS wire rate on both write and read sides.
// ---------------------------------------------------------------------------
__global__ __launch_bounds__(256) void norm_transpose_kernel(
    const float* __restrict__ src, const float* __restrict__ dst,
    __hip_bfloat16* __restrict__ srcT, __hip_bfloat16* __restrict__ dstT) {
    const int s0 = blockIdx.x * 32;
    const int b  = blockIdx.y;
    const float* in = (blockIdx.z == 0 ? src : dst) + (size_t)b * C_DIM * S_DIM;
    __hip_bfloat16* out = (blockIdx.z == 0 ? srcT : dstT) + (size_t)b * S_DIM * C_DIM;

    __shared__ __align__(16) __hip_bfloat16 tile[32][C_DIM];   // 16 KB, swizzled
    __shared__ float red[8][32];
    __shared__ float invn[32];

    const int t = threadIdx.x;
    const int l = t & 31;       // s-offset within block
    const int g = t >> 5;       // c-group 0..7

    // Thread (g,l) owns s = s0+l and c-octets oct = 8q+g, q in [0,4).
    float ss = 0.f;
#pragma unroll
    for (int q = 0; q < 4; ++q) {
        int oct = 8 * q + g;
        union { short8 v; __hip_bfloat16 h[8]; } o;
#pragma unroll
        for (int j = 0; j < 8; ++j) {
            float v = in[(size_t)(oct * 8 + j) * S_DIM + s0 + l];
            ss += v * v;
            o.h[j] = __float2bfloat16(v);
        }
        *(short8*)((char*)&tile[l][0] + ((oct * 16) ^ ((l & 7) << 4))) = o.v;
    }
    red[g][l] = ss;
    __syncthreads();
    if (t < 32) {
        float a = 0.f;
#pragma unroll
        for (int w = 0; w < 8; ++w) a += red[w][t];
        invn[t] = rsqrtf(a);
    }
    __syncthreads();

    // Emit tiled layout: 32x256 elems = 1024 short8 -> 4 iters of 256 thr.
#pragma unroll
    for (int it = 0; it < 4; ++it) {
        int gidx = it * 256 + t;
        int fm   = gidx & 15;          // row within 16-group
        int cg   = (gidx >> 4) & 31;   // k-chunk (8 bf16) == octet index
        int sg   = gidx >> 9;          // row-group within block (0..1)
        int srow = sg * 16 + fm;
        float inv = invn[srow];
        union { short8 v; __hip_bfloat16 h[8]; } u, o;
        u.v = *(const short8*)((const char*)&tile[srow][0]
                               + ((cg * 16) ^ ((srow & 7) << 4)));
#pragma unroll
        for (int j = 0; j < 8; ++j)
            o.h[j] = __float2bfloat16(__bfloat162float(u.h[j]) * inv);
        *(short8*)&out[(size_t)((s0 >> 4) + sg) * 4096 + cg * 128 + fm * 8] = o.v;
    }
}

// ---------------------------------------------------------------------------
// Kernel 2: per-batch GEMM  out[b][m][n] = relu( sum_k A[m][k]*B[n][k] )
// EXACT R6 best-verified version (207.2 us total). R7's 256^2+staging test
// REFUTED the L3-read-traffic theory (+11.7 us) -> reverted. Zero-LDS,
// zero-barrier main loop: fragments stream from the XCD-resident L2 via
// coalesced 1 KB loads, register ping-pong double buffer. Epilogue: LDS
// transpose + dense nontemporal floatx4 stores (full 128-B lines; NT keeps
// the 21 MB/batch C stream from evicting the A/B panels from L2).
// ---------------------------------------------------------------------------
__global__ __launch_bounds__(256, 3) void gemm_relu_kernel(
    const __hip_bfloat16* __restrict__ At, const __hip_bfloat16* __restrict__ Bt,
    float* __restrict__ out) {
    const int id = blockIdx.x;
    const int b  = id & 7;          // batch -> XCD (id%8 round-robin)
    const int q  = id >> 3;
    const int m0 = (q % 18) * 128;
    const int n0 = (q / 18) * 128;

    __shared__ __align__(16) float Cs[64 * 132];

    const int t    = threadIdx.x;
    const int lane = t & 63;
    const int wv   = t >> 6;

    const int fm = lane & 15;
    const int wr = (wv >> 1) << 6;
    const int wc = (wv & 1) << 6;
    const int rq = (lane >> 4) << 2;

    // Per-lane fragment base: tiled layout makes this base + lane*16B.
    const __hip_bfloat16* pA = At + (size_t)b * S_DIM * C_DIM
                             + (size_t)((m0 + wr) >> 4) * 4096 + lane * 8;
    const __hip_bfloat16* pB = Bt + (size_t)b * S_DIM * C_DIM
                             + (size_t)((n0 + wc) >> 4) * 4096 + lane * 8;
    // frag i: +i*4096 (next 16-row group); k-iter ki: +ki*512 (4 k-chunks)

    floatx4 acc[4][4] = {};
    short8 a0[4], b0[4], a1[4], b1[4];

#pragma unroll
    for (int i = 0; i < 4; ++i) {
        a0[i] = *(const short8*)(pA + i * 4096);
        b0[i] = *(const short8*)(pB + i * 4096);
    }

#pragma unroll
    for (int ki = 0; ki < 8; ki += 2) {
        // prefetch iter ki+1 while computing iter ki
#pragma unroll
        for (int i = 0; i < 4; ++i) {
            a1[i] = *(const short8*)(pA + i * 4096 + (ki + 1) * 512);
            b1[i] = *(const short8*)(pB + i * 4096 + (ki + 1) * 512);
        }
        __builtin_amdgcn_s_setprio(1);
#pragma unroll
        for (int i = 0; i < 4; ++i)
#pragma unroll
            for (int j = 0; j < 4; ++j)
                acc[i][j] = __builtin_amdgcn_mfma_f32_16x16x32_bf16(a0[i], b0[j], acc[i][j], 0, 0, 0);
        __builtin_amdgcn_s_setprio(0);

        if (ki + 2 < 8) {
#pragma unroll
            for (int i = 0; i < 4; ++i) {
                a0[i] = *(const short8*)(pA + i * 4096 + (ki + 2) * 512);
                b0[i] = *(const short8*)(pB + i * 4096 + (ki + 2) * 512);
            }
        }
        __builtin_amdgcn_s_setprio(1);
#pragma unroll
        for (int i = 0; i < 4; ++i)
#pragma unroll
            for (int j = 0; j < 4; ++j)
                acc[i][j] = __builtin_amdgcn_mfma_f32_16x16x32_bf16(a1[i], b1[j], acc[i][j], 0, 0, 0);
        __builtin_amdgcn_s_setprio(0);
    }

    // Epilogue: acc -> padded LDS f32 tile -> dense nontemporal floatx4
    // stores (1 KB/wave-instr, full lines), ReLU fused.  Verified mapping.
    float* Cp = out + (size_t)b * S_DIM * S_DIM;
#pragma unroll
    for (int p = 0; p < 2; ++p) {
        __syncthreads();   // prior Cs reads done (and wave convergence)
#pragma unroll
        for (int i2 = 0; i2 < 2; ++i2) {
            int i = 2 * p + i2;
            int slot = (wr >> 1) + i2 * 16 + rq;
#pragma unroll
            for (int j = 0; j < 4; ++j) {
                int col = wc + j * 16 + fm;
#pragma unroll
                for (int r = 0; r < 4; ++r)
                    Cs[(slot + r) * 132 + col] = fmaxf(acc[i][j][r], 0.f);
            }
        }
        __syncthreads();
#pragma unroll
        for (int it = 0; it < 8; ++it) {
            int idx  = it * 256 + t;
            int srow = idx >> 5;
            int c4   = (idx & 31) << 2;
            floatx4 v = *(const floatx4*)&Cs[srow * 132 + c4];
            int lrow = 32 * p + (srow & 31) + ((srow >> 5) << 6);
            __builtin_nontemporal_store(
                v, (floatx4*)&Cp[(size_t)(m0 + lrow) * S_DIM + n0 + c4]);
        }
    }
}

extern "C" void kernel_launch(void* const* d_in, const int* in_sizes, int n_in,
                              void* d_out, int out_size, void* d_ws, size_t ws_size,
                              hipStream_t stream) {
    const float* src = (const float*)d_in[0];
    const float* dst = (const float*)d_in[1];
    float* out = (float*)d_out;

    __hip_bfloat16* srcT = (__hip_bfloat16*)d_ws;
    __hip_bfloat16* dstT = srcT + (size_t)B_DIM * S_DIM * C_DIM;

    dim3 g1(S_DIM / 32, B_DIM, 2);
    norm_transpose_kernel<<<g1, 256, 0, stream>>>(src, dst, srcT, dstT);

    gemm_relu_kernel<<<dim3(B_DIM * 18 * 18), 256, 0, stream>>>(srcT, dstT, out);
}

// Round 9
// 205.065 us; speedup vs baseline: 1.0676x; 1.0238x over previous
//
#include <hip/hip_runtime.h>
#include <hip/hip_bf16.h>

#define B_DIM 8
#define C_DIM 256
#define S_DIM 2304

// srcT/dstT layout: MFMA-fragment-tiled  [B][S/16][C/8][16 rows][8 k]
//   T(s,c) = (s>>4)*4096 + (c>>3)*128 + (s&15)*8 + (c&7)      (elems)
// A wave's A/B fragment load for mfma_16x16x32_bf16 becomes base + lane*16B
// -> one fully coalesced 1 KB global_load_dwordx4 from the XCD-resident L2.

typedef __attribute__((ext_vector_type(8))) short short8;
typedef __attribute__((ext_vector_type(4))) float floatx4;

// ---------------------------------------------------------------------------
// Kernel 1: per-(b,s) L2-normalize over C, f32 [B,C,S] -> bf16 tiled layout.
// R6-verified best: 64 s-rows/block, 256 threads; LDS staging via b128
// writes + XOR swizzle (byteInRow = 16*oct ^ 16*(row&7), row = 512 B):
// full LDS wire rate both sides, zero conflicts. (R8 showed 32-row blocks
// are ~2.7 us WORSE; R3 showed 512-thread is worse. This shape is optimal.)
// ---------------------------------------------------------------------------
__global__ __launch_bounds__(256) void norm_transpose_kernel(
    const float* __restrict__ src, const float* __restrict__ dst,
    __hip_bfloat16* __restrict__ srcT, __hip_bfloat16* __restrict__ dstT) {
    const int s0 = blockIdx.x * 64;
    const int b  = blockIdx.y;
    const float* in = (blockIdx.z == 0 ? src : dst) + (size_t)b * C_DIM * S_DIM;
    __hip_bfloat16* out = (blockIdx.z == 0 ? srcT : dstT) + (size_t)b * S_DIM * C_DIM;

    __shared__ __align__(16) __hip_bfloat16 tile[64][C_DIM];   // 32 KB, swizzled
    __shared__ float red[4][64];
    __shared__ float invn[64];

    const int t  = threadIdx.x;
    const int l  = t & 63;
    const int wv = t >> 6;

    float ss = 0.f;
#pragma unroll 2
    for (int q = 0; q < 8; ++q) {
        int oct = 4 * q + wv;
        union { short8 v; __hip_bfloat16 h[8]; } o;
#pragma unroll
        for (int j = 0; j < 8; ++j) {
            float v = in[(size_t)(oct * 8 + j) * S_DIM + s0 + l];
            ss += v * v;
            o.h[j] = __float2bfloat16(v);
        }
        *(short8*)((char*)&tile[l][0] + ((oct * 16) ^ ((l & 7) << 4))) = o.v;
    }
    red[wv][l] = ss;
    __syncthreads();
    if (t < 64) invn[t] = rsqrtf(red[0][t] + red[1][t] + red[2][t] + red[3][t]);
    __syncthreads();

#pragma unroll
    for (int it = 0; it < 8; ++it) {
        int gidx = it * 256 + t;
        int fm   = gidx & 15;
        int cg   = (gidx >> 4) & 31;
        int sg   = gidx >> 9;
        int srow = sg * 16 + fm;
        float inv = invn[srow];
        union { short8 v; __hip_bfloat16 h[8]; } u, o;
        u.v = *(const short8*)((const char*)&tile[srow][0]
                               + ((cg * 16) ^ ((srow & 7) << 4)));
#pragma unroll
        for (int j = 0; j < 8; ++j)
            o.h[j] = __float2bfloat16(__bfloat162float(u.h[j]) * inv);
        *(short8*)&out[(size_t)((s0 >> 4) + sg) * 4096 + cg * 128 + fm * 8] = o.v;
    }
}

// ---------------------------------------------------------------------------
// Kernel 2: per-batch GEMM  out[b][m][n] = relu( sum_k A[m][k]*B[n][k] )
// R6-verified best (207.2 us total). Zero-LDS, zero-barrier main loop:
// fragments stream from the XCD-resident L2 via coalesced 1 KB loads,
// register ping-pong double buffer. Epilogue: LDS transpose + dense
// nontemporal floatx4 stores (full 128-B lines; NT keeps the 21 MB/batch
// C stream from evicting the A/B panels from L2).
// Tested and rejected alternatives: LDS-pipelined loop (tie), 256^2-staged
// tile (+11.7 us), direct scalar NT stores (+5.5 us).
// ---------------------------------------------------------------------------
__global__ __launch_bounds__(256, 3) void gemm_relu_kernel(
    const __hip_bfloat16* __restrict__ At, const __hip_bfloat16* __restrict__ Bt,
    float* __restrict__ out) {
    const int id = blockIdx.x;
    const int b  = id & 7;          // batch -> XCD (id%8 round-robin)
    const int q  = id >> 3;
    const int m0 = (q % 18) * 128;
    const int n0 = (q / 18) * 128;

    __shared__ __align__(16) float Cs[64 * 132];

    const int t    = threadIdx.x;
    const int lane = t & 63;
    const int wv   = t >> 6;

    const int fm = lane & 15;
    const int wr = (wv >> 1) << 6;
    const int wc = (wv & 1) << 6;
    const int rq = (lane >> 4) << 2;

    // Per-lane fragment base: tiled layout makes this base + lane*16B.
    const __hip_bfloat16* pA = At + (size_t)b * S_DIM * C_DIM
                             + (size_t)((m0 + wr) >> 4) * 4096 + lane * 8;
    const __hip_bfloat16* pB = Bt + (size_t)b * S_DIM * C_DIM
                             + (size_t)((n0 + wc) >> 4) * 4096 + lane * 8;
    // frag i: +i*4096 (next 16-row group); k-iter ki: +ki*512 (4 k-chunks)

    floatx4 acc[4][4] = {};
    short8 a0[4], b0[4], a1[4], b1[4];

#pragma unroll
    for (int i = 0; i < 4; ++i) {
        a0[i] = *(const short8*)(pA + i * 4096);
        b0[i] = *(const short8*)(pB + i * 4096);
    }

#pragma unroll
    for (int ki = 0; ki < 8; ki += 2) {
        // prefetch iter ki+1 while computing iter ki
#pragma unroll
        for (int i = 0; i < 4; ++i) {
            a1[i] = *(const short8*)(pA + i * 4096 + (ki + 1) * 512);
            b1[i] = *(const short8*)(pB + i * 4096 + (ki + 1) * 512);
        }
        __builtin_amdgcn_s_setprio(1);
#pragma unroll
        for (int i = 0; i < 4; ++i)
#pragma unroll
            for (int j = 0; j < 4; ++j)
                acc[i][j] = __builtin_amdgcn_mfma_f32_16x16x32_bf16(a0[i], b0[j], acc[i][j], 0, 0, 0);
        __builtin_amdgcn_s_setprio(0);

        if (ki + 2 < 8) {
#pragma unroll
            for (int i = 0; i < 4; ++i) {
                a0[i] = *(const short8*)(pA + i * 4096 + (ki + 2) * 512);
                b0[i] = *(const short8*)(pB + i * 4096 + (ki + 2) * 512);
            }
        }
        __builtin_amdgcn_s_setprio(1);
#pragma unroll
        for (int i = 0; i < 4; ++i)
#pragma unroll
            for (int j = 0; j < 4; ++j)
                acc[i][j] = __builtin_amdgcn_mfma_f32_16x16x32_bf16(a1[i], b1[j], acc[i][j], 0, 0, 0);
        __builtin_amdgcn_s_setprio(0);
    }

    // Epilogue: acc -> padded LDS f32 tile -> dense nontemporal floatx4
    // stores (1 KB/wave-instr, full lines), ReLU fused.  Verified mapping.
    float* Cp = out + (size_t)b * S_DIM * S_DIM;
#pragma unroll
    for (int p = 0; p < 2; ++p) {
        __syncthreads();   // prior Cs reads done (and wave convergence)
#pragma unroll
        for (int i2 = 0; i2 < 2; ++i2) {
            int i = 2 * p + i2;
            int slot = (wr >> 1) + i2 * 16 + rq;
#pragma unroll
            for (int j = 0; j < 4; ++j) {
                int col = wc + j * 16 + fm;
#pragma unroll
                for (int r = 0; r < 4; ++r)
                    Cs[(slot + r) * 132 + col] = fmaxf(acc[i][j][r], 0.f);
            }
        }
        __syncthreads();
#pragma unroll
        for (int it = 0; it < 8; ++it) {
            int idx  = it * 256 + t;
            int srow = idx >> 5;
            int c4   = (idx & 31) << 2;
            floatx4 v = *(const floatx4*)&Cs[srow * 132 + c4];
            int lrow = 32 * p + (srow & 31) + ((srow >> 5) << 6);
            __builtin_nontemporal_store(
                v, (floatx4*)&Cp[(size_t)(m0 + lrow) * S_DIM + n0 + c4]);
        }
    }
}

extern "C" void kernel_launch(void* const* d_in, const int* in_sizes, int n_in,
                              void* d_out, int out_size, void* d_ws, size_t ws_size,
                              hipStream_t stream) {
    const float* src = (const float*)d_in[0];
    const float* dst = (const float*)d_in[1];
    float* out = (float*)d_out;

    __hip_bfloat16* srcT = (__hip_bfloat16*)d_ws;
    __hip_bfloat16* dstT = srcT + (size_t)B_DIM * S_DIM * C_DIM;

    dim3 g1(S_DIM / 64, B_DIM, 2);
    norm_transpose_kernel<<<g1, 256, 0, stream>>>(src, dst, srcT, dstT);

    gemm_relu_kernel<<<dim3(B_DIM * 18 * 18), 256, 0, stream>>>(srcT, dstT, out);
}